// Round 1
// baseline (1345.415 us; speedup 1.0000x reference)
//
#include <hip/hip_runtime.h>
#include <stdint.h>

#define B_TOT   16384
#define NNBR    20
#define NODE_D  172
#define TIME_D  100
#define KEY_D   444
#define OUT_D   272
#define KPAD    448
#define CHUNKS  4
#define CB      (B_TOT/CHUNKS)   // 4096 batch rows per chunk
#define CROWS   (CB*NNBR)        // 81920 kv rows per chunk
#define K2PAD   288
#define SA_KV   456              // A panel LDS stride (elems), kv_gemm
#define SA_Q    296              // A panel LDS stride (elems), q/resid
#define BKV_CF  36               // col frags in packed Bkv (576 padded cols)
#define BKV_KS  (BKV_CF*512)     // shorts per k-step block = 18432

typedef __attribute__((ext_vector_type(4))) float          f32x4;
typedef __attribute__((ext_vector_type(8))) short          bfx8;
typedef __attribute__((ext_vector_type(8))) unsigned short usx8;

__device__ __forceinline__ unsigned short f2bf(float f) {
  union { float f; unsigned u; } v; v.f = f;
  return (unsigned short)((v.u + 0x7FFFu + ((v.u >> 16) & 1u)) >> 16);  // RTNE
}
__device__ __forceinline__ float bf2f(unsigned short h) {
  union { unsigned u; float f; } v; v.u = ((unsigned)h) << 16; return v.f;
}
__device__ __forceinline__ usx8 pack8(f32x4 a, f32x4 b) {
  usx8 h;
  h[0] = f2bf(a[0]); h[1] = f2bf(a[1]); h[2] = f2bf(a[2]); h[3] = f2bf(a[3]);
  h[4] = f2bf(b[0]); h[5] = f2bf(b[1]); h[6] = f2bf(b[2]); h[7] = f2bf(b[3]);
  return h;
}

// ---------------------------------------------------------------- pack weights
// Bkv is packed in MFMA-fragment order: idx = ((ks*36 + cf)*64 + lane)*8 + j
// lane = quad*16 + l15 ; col = cf*16 + l15 ; k = ks*32 + quad*8 + j.
// A wave's B-frag load is then ONE contiguous 1KB access (vs 16x64B segments).
__global__ __launch_bounds__(256) void pack_w(
    const float* __restrict__ Wk, const float* __restrict__ Wv,
    const float* __restrict__ Wq, const float* __restrict__ Wr,
    unsigned short* __restrict__ Bkv, unsigned short* __restrict__ Bq,
    unsigned short* __restrict__ Br) {
  int idx = blockIdx.x * 256 + threadIdx.x;
  if (idx < 14 * BKV_KS) {
    int j = idx & 7, ln = (idx >> 3) & 63, fid = idx >> 9;
    int cf = fid % BKV_CF, ks = fid / BKV_CF;
    int col = cf * 16 + (ln & 15);
    int k = ks * 32 + (ln >> 4) * 8 + j;
    float v = 0.f;
    if (col < 2 * OUT_D && k < KEY_D)
      v = (col < OUT_D) ? Wk[col * KEY_D + k] : Wv[(col - OUT_D) * KEY_D + k];
    Bkv[idx] = f2bf(v);
  }
  if (idx < K2PAD * K2PAD) {
    int j = idx / K2PAD, k = idx % K2PAD;
    bool in = (j < OUT_D) && (k < OUT_D);
    Bq[idx] = f2bf(in ? Wq[j * OUT_D + k] : 0.f);
    Br[idx] = f2bf(in ? Wr[j * OUT_D + k] : 0.f);
  }
}

// ---------------------------------------------------------------- K/V GEMM
__device__ __forceinline__ f32x4 ld_kv(const float* pn, const float* pe,
                                       const float* pt, int k) {
  if (k < NODE_D)     return *(const f32x4*)(pn + k);
  if (k < 2*NODE_D)   return *(const f32x4*)(pe + (k - NODE_D));
  if (k < KEY_D)      return *(const f32x4*)(pt + (k - 2*NODE_D));
  return (f32x4){0.f, 0.f, 0.f, 0.f};
}

// One col-pass of the kv GEMM: wave computes 64 rows x NF*16 cols.
// NF=4: 16 MFMA per k-step vs 8 loads (4 B global + 4 A LDS), B prefetched
// 2 k-steps ahead, A 1 ahead. bp points at this wave's first frag (lane incl.).
template<int NF>
__device__ __forceinline__ void kv_pass(
    const unsigned short* __restrict__ ap,
    const unsigned short* __restrict__ bp,
    unsigned short* __restrict__ sw, unsigned short* __restrict__ KV,
    int m0, int c0, int l, int l15, int quad) {
  f32x4 acc[4][NF];
#pragma unroll
  for (int mf = 0; mf < 4; ++mf)
#pragma unroll
    for (int nf = 0; nf < NF; ++nf) acc[mf][nf] = (f32x4){0, 0, 0, 0};

  bfx8 b0[NF], b1[NF], a0[4];
#pragma unroll
  for (int nf = 0; nf < NF; ++nf) {
    b0[nf] = *(const bfx8*)(bp + nf * 512);
    b1[nf] = *(const bfx8*)(bp + BKV_KS + nf * 512);
  }
#pragma unroll
  for (int mf = 0; mf < 4; ++mf) a0[mf] = *(const bfx8*)(ap + mf * 16 * SA_KV);

#pragma unroll
  for (int ks = 0; ks < 14; ++ks) {
    const unsigned short* bpp = bp + (size_t)((ks + 2 < 14) ? ks + 2 : 0) * BKV_KS;
    const unsigned short* app = ap + ((ks + 1 < 14) ? ks + 1 : 0) * 32;
    bfx8 b2[NF], a1[4];
#pragma unroll
    for (int nf = 0; nf < NF; ++nf) b2[nf] = *(const bfx8*)(bpp + nf * 512);
#pragma unroll
    for (int mf = 0; mf < 4; ++mf) a1[mf] = *(const bfx8*)(app + mf * 16 * SA_KV);
#pragma unroll
    for (int mf = 0; mf < 4; ++mf)
#pragma unroll
      for (int nf = 0; nf < NF; ++nf)
        acc[mf][nf] = __builtin_amdgcn_mfma_f32_16x16x32_bf16(
            a0[mf], b0[nf], acc[mf][nf], 0, 0, 0);
#pragma unroll
    for (int nf = 0; nf < NF; ++nf) { b0[nf] = b1[nf]; b1[nf] = b2[nf]; }
#pragma unroll
    for (int mf = 0; mf < 4; ++mf) a0[mf] = a1[mf];
  }

  // epilogue: wave-private LDS bounce -> 16B-granule global stores
#pragma unroll
  for (int h = 0; h < (NF + 1) / 2; ++h) {
#pragma unroll
    for (int mf = 0; mf < 4; ++mf)
#pragma unroll
      for (int e = 0; e < ((NF > 1) ? 2 : 1); ++e)
#pragma unroll
        for (int r = 0; r < 4; ++r)
          sw[(mf * 16 + quad * 4 + r) * 40 + e * 16 + l15] =
              f2bf(acc[mf][h * 2 + e][r]);
    if (NF > 1) {
#pragma unroll
      for (int j = 0; j < 4; ++j) {
        const int idx = j * 64 + l;
        const int row = idx >> 2, o = idx & 3;
        usx8 v = *(const usx8*)(sw + row * 40 + o * 8);
        *(usx8*)((char*)KV + (size_t)(m0 + row) * 1088 +
                 (size_t)(c0 + h * 32 + o * 8) * 2) = v;
      }
    } else {
#pragma unroll
      for (int j = 0; j < 2; ++j) {
        const int idx = j * 64 + l;
        const int row = idx >> 1, o = idx & 1;
        usx8 v = *(const usx8*)(sw + row * 40 + o * 8);
        *(usx8*)((char*)KV + (size_t)(m0 + row) * 1088 +
                 (size_t)(c0 + o * 8) * 2) = v;
      }
    }
  }
}

// Block: 64 kv-rows x 544 cols. A panel staged to LDS once; barrier-free
// passes: each wave owns a 64-col slice per pass (2 full passes + 32-col tail).
__global__ __launch_bounds__(256, 2) void kv_gemm(
    const float* __restrict__ nbrF, const float* __restrict__ edgeF,
    const float* __restrict__ timeF, const unsigned short* __restrict__ Bkv,
    unsigned short* __restrict__ KV, int row0) {
  __shared__ unsigned short sA[64 * SA_KV];      // 58368 B
  __shared__ unsigned short scr[4 * 64 * 40];    // 20480 B
  const int t = threadIdx.x;
  const int w = t >> 6, l = t & 63, l15 = l & 15, quad = l >> 4;
  const int m0 = blockIdx.x * 64;
  // ---- stage A panel (once)
  {
    const int r = t >> 2, qt = t & 3;
    const long grow = (long)row0 + m0 + r;
    const float* pn = nbrF + grow * NODE_D;
    const float* pe = edgeF + grow * NODE_D;
    const float* pt = timeF + grow * TIME_D;
#pragma unroll
    for (int i = 0; i < 14; ++i) {
      const int k = (qt + 4 * i) * 8;
      f32x4 v0 = ld_kv(pn, pe, pt, k);
      f32x4 v1 = ld_kv(pn, pe, pt, k + 4);
      *(usx8*)&sA[r * SA_KV + k] = pack8(v0, v1);
    }
  }
  __syncthreads();

  const unsigned short* ap = sA + l15 * SA_KV + quad * 8;
  unsigned short* sw = scr + w * 2560;
#pragma unroll 1
  for (int nt = 0; nt < 2; ++nt) {
    const int cf0 = nt * 16 + w * 4;              // cols cf0*16 .. +63
    kv_pass<4>(ap, Bkv + (size_t)cf0 * 512 + (size_t)l * 8, sw, KV,
               m0, cf0 * 16, l, l15, quad);
  }
  if (w < 2) {                                    // tail cols 512..543
    const int cf0 = 32 + w;
    kv_pass<1>(ap, Bkv + (size_t)cf0 * 512 + (size_t)l * 8, sw, KV,
               m0, cf0 * 16, l, l15, quad);
  }
}

// ---------------------------------------------------------------- Q GEMM
__global__ __launch_bounds__(256) void q_gemm(
    const float* __restrict__ nodeF, const float* __restrict__ timeF,
    const unsigned short* __restrict__ Bq, unsigned short* __restrict__ Q) {
  __shared__ unsigned short sA[64 * SA_Q];  // 37888 B
  const int t = threadIdx.x;
  const int w = t >> 6, l = t & 63, l15 = l & 15, quad = l >> 4;
  const int m0 = blockIdx.x * 64;
  {
    const int r = t >> 2, qt = t & 3;
    const float* pn = nodeF + (size_t)(m0 + r) * NODE_D;
    const float* pt = timeF + (size_t)(m0 + r) * TIME_D;
#pragma unroll
    for (int i = 0; i < 9; ++i) {
      const int k = (qt + 4 * i) * 8;
      f32x4 v0, v1;
      v0 = (k < NODE_D) ? *(const f32x4*)(pn + k)
         : (k < OUT_D)  ? *(const f32x4*)(pt + (k - NODE_D)) : (f32x4){0,0,0,0};
      int k4 = k + 4;
      v1 = (k4 < NODE_D) ? *(const f32x4*)(pn + k4)
         : (k4 < OUT_D)  ? *(const f32x4*)(pt + (k4 - NODE_D)) : (f32x4){0,0,0,0};
      *(usx8*)&sA[r * SA_Q + k] = pack8(v0, v1);
    }
  }
  __syncthreads();
  const unsigned short* ap = sA + (w * 16 + l15) * SA_Q + quad * 8;
  const unsigned short* bp = Bq + (size_t)l15 * K2PAD + quad * 8;
  f32x4 acc[17];
#pragma unroll
  for (int nf = 0; nf < 17; ++nf) acc[nf] = (f32x4){0,0,0,0};
#pragma unroll
  for (int k0 = 0; k0 < K2PAD; k0 += 32) {
    bfx8 a = *(const bfx8*)(ap + k0);
#pragma unroll
    for (int nf = 0; nf < 17; ++nf) {
      bfx8 b = *(const bfx8*)(bp + nf * 16 * K2PAD + k0);
      acc[nf] = __builtin_amdgcn_mfma_f32_16x16x32_bf16(a, b, acc[nf], 0, 0, 0);
    }
  }
#pragma unroll
  for (int nf = 0; nf < 17; ++nf)
#pragma unroll
    for (int r = 0; r < 4; ++r) {
      const size_t row = m0 + w * 16 + quad * 4 + r;
      Q[row * K2PAD + nf * 16 + l15] = f2bf(acc[nf][r]);
    }
}

// ---------------------------------------------------------------- attention
__global__ __launch_bounds__(256) void attn_k(
    const unsigned short* __restrict__ Q, const unsigned short* __restrict__ KV,
    const int* __restrict__ masks, unsigned short* __restrict__ At, int b0) {
  const int bl = blockIdx.x;
  const int b = b0 + bl;
  const int h = threadIdx.x >> 6, l = threadIdx.x & 63;
  const bool hi = (l < 4);
  const unsigned short* kvb = KV + (size_t)bl * 20 * 544 + h * 68;
  const unsigned short* qp  = Q + (size_t)b * K2PAD + h * 68;
  const float q1 = bf2f(qp[l]);
  const float q2 = hi ? bf2f(qp[64 + l]) : 0.f;
  int mk[20];
#pragma unroll
  for (int n = 0; n < 20; ++n) mk[n] = masks[b * 20 + n];
  float s[20];
#pragma unroll
  for (int n = 0; n < 20; ++n) {
    const unsigned short* kn = kvb + n * 544;
    float p = q1 * bf2f(kn[l]);
    if (hi) p += q2 * bf2f(kn[64 + l]);
#pragma unroll
    for (int o = 32; o > 0; o >>= 1) p += __shfl_xor(p, o);
    s[n] = p;
  }
  const float scale = 0.12126781251816648f;  // 68^-0.5
  float mx = -1e30f;
#pragma unroll
  for (int n = 0; n < 20; ++n) {
    s[n] = mk[n] ? s[n] * scale : -1e10f;
    mx = fmaxf(mx, s[n]);
  }
  float sum = 0.f;
#pragma unroll
  for (int n = 0; n < 20; ++n) { s[n] = __expf(s[n] - mx); sum += s[n]; }
  const float inv = 1.f / sum;
  float o1 = 0.f, o2 = 0.f;
#pragma unroll
  for (int n = 0; n < 20; ++n) {
    const float pn = s[n] * inv;
    const unsigned short* vn = kvb + n * 544 + 272;
    o1 += pn * bf2f(vn[l]);
    if (hi) o2 += pn * bf2f(vn[64 + l]);
  }
  At[(size_t)b * K2PAD + h * 68 + l] = f2bf(o1);
  if (hi) At[(size_t)b * K2PAD + h * 68 + 64 + l] = f2bf(o2);
  if (threadIdx.x < 16) At[(size_t)b * K2PAD + 272 + threadIdx.x] = 0;
}

// ---------------------------------------------------------------- residual FC + LN
__global__ __launch_bounds__(256) void resid_ln(
    const unsigned short* __restrict__ At, const unsigned short* __restrict__ Br,
    const float* __restrict__ nodeF, const float* __restrict__ timeF,
    const float* __restrict__ brv, const float* __restrict__ gammav,
    const float* __restrict__ betav, float* __restrict__ Out) {
  __shared__ unsigned short sA[64 * SA_Q];
  const int t = threadIdx.x;
  const int w = t >> 6, l = t & 63, l15 = l & 15, quad = l >> 4;
  const int m0 = blockIdx.x * 64;
#pragma unroll
  for (int i = 0; i < 9; ++i) {
    const int idx = i * 256 + t;
    const int row = idx / 36, g = idx % 36;
    usx8 v = *(const usx8*)(At + (size_t)(m0 + row) * K2PAD + g * 8);
    *(usx8*)&sA[row * SA_Q + g * 8] = v;
  }
  __syncthreads();
  const unsigned short* ap = sA + (w * 16 + l15) * SA_Q + quad * 8;
  const unsigned short* bp = Br + (size_t)l15 * K2PAD + quad * 8;
  f32x4 acc[17];
#pragma unroll
  for (int nf = 0; nf < 17; ++nf) acc[nf] = (f32x4){0,0,0,0};
#pragma unroll
  for (int k0 = 0; k0 < K2PAD; k0 += 32) {
    bfx8 a = *(const bfx8*)(ap + k0);
#pragma unroll
    for (int nf = 0; nf < 17; ++nf) {
      bfx8 b = *(const bfx8*)(bp + nf * 16 * K2PAD + k0);
      acc[nf] = __builtin_amdgcn_mfma_f32_16x16x32_bf16(a, b, acc[nf], 0, 0, 0);
    }
  }
  float sum[4] = {0.f, 0.f, 0.f, 0.f}, sq[4] = {0.f, 0.f, 0.f, 0.f};
#pragma unroll
  for (int nf = 0; nf < 17; ++nf) {
    const int col = nf * 16 + l15;
    const float bias = brv[col];
#pragma unroll
    for (int r = 0; r < 4; ++r) {
      const size_t row = m0 + w * 16 + quad * 4 + r;
      const float res = (col < NODE_D) ? nodeF[row * NODE_D + col]
                                       : timeF[row * TIME_D + (col - NODE_D)];
      const float x = acc[nf][r] + bias + res;
      acc[nf][r] = x;
      sum[r] += x; sq[r] += x * x;
    }
  }
#pragma unroll
  for (int r = 0; r < 4; ++r)
#pragma unroll
    for (int o = 1; o < 16; o <<= 1) {
      sum[r] += __shfl_xor(sum[r], o);
      sq[r]  += __shfl_xor(sq[r], o);
    }
  float mean[4], rstd[4];
#pragma unroll
  for (int r = 0; r < 4; ++r) {
    mean[r] = sum[r] * (1.f / OUT_D);
    const float var = sq[r] * (1.f / OUT_D) - mean[r] * mean[r];
    rstd[r] = rsqrtf(var + 1e-5f);
  }
#pragma unroll
  for (int nf = 0; nf < 17; ++nf) {
    const int col = nf * 16 + l15;
    const float g_ = gammav[col], b_ = betav[col];
#pragma unroll
    for (int r = 0; r < 4; ++r) {
      const size_t row = m0 + w * 16 + quad * 4 + r;
      Out[row * OUT_D + col] = (acc[nf][r] - mean[r]) * rstd[r] * g_ + b_;
    }
  }
}

// ---------------------------------------------------------------- launch
extern "C" void kernel_launch(void* const* d_in, const int* in_sizes, int n_in,
                              void* d_out, int out_size, void* d_ws, size_t ws_size,
                              hipStream_t stream) {
  const float* nodeF = (const float*)d_in[0];
  const float* ntime = (const float*)d_in[1];
  const float* nbrF  = (const float*)d_in[2];
  const float* nbrT  = (const float*)d_in[3];
  const float* nbrE  = (const float*)d_in[4];
  const int*   mask  = (const int*)d_in[5];
  const float* Wq = (const float*)d_in[6];
  const float* Wk = (const float*)d_in[7];
  const float* Wv = (const float*)d_in[8];
  const float* Wr = (const float*)d_in[9];
  const float* brv = (const float*)d_in[10];
  const float* gv  = (const float*)d_in[11];
  const float* bv  = (const float*)d_in[12];
  float* out = (float*)d_out;

  char* p = (char*)d_ws;
  auto take = [&](size_t bytes) {
    char* q = p; p += (bytes + 255) & ~(size_t)255; return q;
  };
  unsigned short* Bkv = (unsigned short*)take((size_t)14 * BKV_KS * 2);
  unsigned short* Bq  = (unsigned short*)take((size_t)K2PAD * K2PAD * 2);
  unsigned short* Brm = (unsigned short*)take((size_t)K2PAD * K2PAD * 2);
  unsigned short* Qm  = (unsigned short*)take((size_t)B_TOT * K2PAD * 2);
  unsigned short* At  = (unsigned short*)take((size_t)B_TOT * K2PAD * 2);
  unsigned short* KV  = (unsigned short*)take((size_t)CROWS * 2 * OUT_D * 2);

  pack_w<<<dim3(1120), dim3(256), 0, stream>>>(Wk, Wv, Wq, Wr, Bkv, Bq, Brm);
  q_gemm<<<dim3(B_TOT / 64), dim3(256), 0, stream>>>(nodeF, ntime, Bq, Qm);
  for (int c = 0; c < CHUNKS; ++c) {
    kv_gemm<<<dim3(CROWS / 64), dim3(256), 0, stream>>>(
        nbrF, nbrE, nbrT, Bkv, KV, c * CROWS);
    attn_k<<<dim3(CB), dim3(256), 0, stream>>>(Qm, KV, mask, At, c * CB);
  }
  resid_ln<<<dim3(B_TOT / 64), dim3(256), 0, stream>>>(
      At, Brm, nodeF, ntime, brv, gv, bv, out);
}

// Round 2
// 1004.071 us; speedup vs baseline: 1.3400x; 1.3400x over previous
//
#include <hip/hip_runtime.h>
#include <stdint.h>

#define B_TOT   16384
#define NNBR    20
#define NODE_D  172
#define TIME_D  100
#define KEY_D   444
#define OUT_D   272
#define K2PAD   288
#define SA_Q    296              // A panel LDS stride (elems) for u_gemm
#define NCH     2
#define CB2     (B_TOT/NCH)      // 8192 rows per chunk
#define UD      448              // per-head padded key dim
#define UCOLS   (4*UD)           // 1792
#define G_NF    112              // col frags in Gp (1792/16)
#define G_KS    9                // k-steps in Gp (288/32)
#define M_NF    17               // col frags in M2p (272/16)
#define M_KS    56               // k-steps in M2p (1792/32)
#define GP_N    (G_KS*G_NF*64)   // 64512 usx8 outputs
#define MP_N    (M_KS*M_NF*64)   // 60928 usx8 outputs

typedef __attribute__((ext_vector_type(4))) float          f32x4;
typedef __attribute__((ext_vector_type(8))) short          bfx8;
typedef __attribute__((ext_vector_type(8))) unsigned short usx8;

__device__ __forceinline__ unsigned short f2bf(float f) {
  union { float f; unsigned u; } v; v.f = f;
  return (unsigned short)((v.u + 0x7FFFu + ((v.u >> 16) & 1u)) >> 16);  // RTNE
}
__device__ __forceinline__ float bf2f(unsigned short h) {
  union { unsigned u; float f; } v; v.u = ((unsigned)h) << 16; return v.f;
}
__device__ __forceinline__ usx8 pack8(f32x4 a, f32x4 b) {
  usx8 h;
  h[0] = f2bf(a[0]); h[1] = f2bf(a[1]); h[2] = f2bf(a[2]); h[3] = f2bf(a[3]);
  h[4] = f2bf(b[0]); h[5] = f2bf(b[1]); h[6] = f2bf(b[2]); h[7] = f2bf(b[3]);
  return h;
}

// ------------------------------------------------------------- fold weights
// G[i, h*448+d]  = sum_j Wq[h*68+j, i] * Wk[h*68+j, d]   (scores:  s = a . (qin@G))
// M2[h*448+d, i] = sum_j Wr[i, h*68+j] * Wv[h*68+j, d]   (output: out = w @ M2)
// Both stored in MFMA fragment order: ((ks*NF + cf)*64 + lane)*8 + j,
// lane=(quad,l15): col = cf*16+l15, k = ks*32 + quad*8 + j.
__global__ __launch_bounds__(256) void pack_gm(
    const float* __restrict__ Wq, const float* __restrict__ Wk,
    const float* __restrict__ Wv, const float* __restrict__ Wr,
    unsigned short* __restrict__ Gp, unsigned short* __restrict__ M2p) {
  const int tid = blockIdx.x * 256 + threadIdx.x;
  f32x4 accA = (f32x4){0,0,0,0}, accB = (f32x4){0,0,0,0};
  if (tid < GP_N) {
    const int ln = tid & 63, fid = tid >> 6;
    const int cf = fid % G_NF, ks = fid / G_NF;
    const int col = cf * 16 + (ln & 15);
    const int h = col / UD, d = col % UD;
    const int i0 = ks * 32 + (ln >> 4) * 8;
    if (i0 < OUT_D && d < KEY_D) {
      const float* wqp = Wq + (size_t)(h * 68) * OUT_D + i0;
      const float* wkp = Wk + (size_t)(h * 68) * KEY_D + d;
      for (int j = 0; j < 68; ++j) {
        const float wk = wkp[(size_t)j * KEY_D];
        const f32x4 q0 = *(const f32x4*)(wqp + (size_t)j * OUT_D);
        const f32x4 q1 = *(const f32x4*)(wqp + (size_t)j * OUT_D + 4);
        accA += q0 * wk; accB += q1 * wk;
      }
    }
    *(usx8*)(Gp + (size_t)tid * 8) = pack8(accA, accB);
  } else if (tid < GP_N + MP_N) {
    const int t2 = tid - GP_N;
    const int ln = t2 & 63, fid = t2 >> 6;
    const int cf = fid % M_NF, ks = fid / M_NF;
    const int col = cf * 16 + (ln & 15);            // output col i < 272
    const int k0 = ks * 32 + (ln >> 4) * 8;
    const int h = k0 / UD, dd = k0 % UD;
    if (dd < KEY_D) {                               // dd <= 440, 8-aligned
      const float* wrp = Wr + (size_t)col * OUT_D + h * 68;
      const float* wvp = Wv + (size_t)(h * 68) * KEY_D + dd;
      const bool full = (dd <= 432);
      for (int j = 0; j < 68; ++j) {
        const float wr = wrp[j];
        const f32x4 v0 = *(const f32x4*)(wvp + (size_t)j * KEY_D);
        accA += v0 * wr;
        if (full) {
          const f32x4 v1 = *(const f32x4*)(wvp + (size_t)j * KEY_D + 4);
          accB += v1 * wr;
        }
      }
    }
    *(usx8*)(M2p + (size_t)t2 * 8) = pack8(accA, accB);
  }
}

// ------------------------------------------------------------- u = qin @ G
// Block: 64 rows x 256 cols (cb of 7). 4 waves, wave = 4 col frags, K=288 (9 ks).
__global__ __launch_bounds__(256) void u_gemm(
    const float* __restrict__ nodeF, const float* __restrict__ timeF,
    const unsigned short* __restrict__ Gp, unsigned short* __restrict__ U,
    int row0) {
  __shared__ unsigned short sA[64 * SA_Q];       // 37888 B
  __shared__ unsigned short scr[4 * 64 * 40];    // 20480 B
  const int t = threadIdx.x;
  const int w = t >> 6, l = t & 63, l15 = l & 15, quad = l >> 4;
  const int rb = blockIdx.x % (CB2 / 64), cb = blockIdx.x / (CB2 / 64);
  const int lrow0 = rb * 64;                     // local row (within chunk)
  {
    const int r = t >> 2, qt = t & 3;
    const size_t grow = (size_t)row0 + lrow0 + r;
    const float* pn = nodeF + grow * NODE_D;
    const float* pt = timeF + grow * TIME_D;
#pragma unroll
    for (int i = 0; i < 9; ++i) {
      const int k = (qt + 4 * i) * 8;
      f32x4 v0, v1;
      v0 = (k < NODE_D) ? *(const f32x4*)(pn + k)
         : (k < OUT_D)  ? *(const f32x4*)(pt + (k - NODE_D)) : (f32x4){0,0,0,0};
      const int k4 = k + 4;
      v1 = (k4 < NODE_D) ? *(const f32x4*)(pn + k4)
         : (k4 < OUT_D)  ? *(const f32x4*)(pt + (k4 - NODE_D)) : (f32x4){0,0,0,0};
      *(usx8*)&sA[r * SA_Q + k] = pack8(v0, v1);
    }
  }
  __syncthreads();

  const unsigned short* ap = sA + l15 * SA_Q + quad * 8;
  const int cf0 = cb * 16 + w * 4;
  const unsigned short* bp = Gp + (size_t)cf0 * 512 + (size_t)l * 8;
  f32x4 acc[4][4];
#pragma unroll
  for (int mf = 0; mf < 4; ++mf)
#pragma unroll
    for (int nf = 0; nf < 4; ++nf) acc[mf][nf] = (f32x4){0, 0, 0, 0};

  bfx8 bc[4], ac[4];
#pragma unroll
  for (int nf = 0; nf < 4; ++nf) bc[nf] = *(const bfx8*)(bp + nf * 512);
#pragma unroll
  for (int mf = 0; mf < 4; ++mf) ac[mf] = *(const bfx8*)(ap + mf * 16 * SA_Q);
#pragma unroll
  for (int ks = 0; ks < G_KS; ++ks) {
    const int kn = (ks + 1 < G_KS) ? ks + 1 : 0;
    bfx8 bn[4], an[4];
#pragma unroll
    for (int nf = 0; nf < 4; ++nf)
      bn[nf] = *(const bfx8*)(bp + (size_t)kn * (G_NF * 512) + nf * 512);
#pragma unroll
    for (int mf = 0; mf < 4; ++mf)
      an[mf] = *(const bfx8*)(ap + kn * 32 + mf * 16 * SA_Q);
#pragma unroll
    for (int mf = 0; mf < 4; ++mf)
#pragma unroll
      for (int nf = 0; nf < 4; ++nf)
        acc[mf][nf] = __builtin_amdgcn_mfma_f32_16x16x32_bf16(
            ac[mf], bc[nf], acc[mf][nf], 0, 0, 0);
#pragma unroll
    for (int nf = 0; nf < 4; ++nf) bc[nf] = bn[nf];
#pragma unroll
    for (int mf = 0; mf < 4; ++mf) ac[mf] = an[mf];
  }
  // epilogue: wave-private LDS bounce -> 16B stores (U local rows, pitch 3584B)
  unsigned short* sw = scr + w * 2560;
  const int c0 = cf0 * 16;
#pragma unroll
  for (int h = 0; h < 2; ++h) {
#pragma unroll
    for (int mf = 0; mf < 4; ++mf)
#pragma unroll
      for (int e = 0; e < 2; ++e)
#pragma unroll
        for (int r = 0; r < 4; ++r)
          sw[(mf * 16 + quad * 4 + r) * 40 + e * 16 + l15] =
              f2bf(acc[mf][h * 2 + e][r]);
#pragma unroll
    for (int j = 0; j < 4; ++j) {
      const int idx = j * 64 + l;
      const int row = idx >> 2, o = idx & 3;
      usx8 v = *(const usx8*)(sw + row * 40 + o * 8);
      *(usx8*)((char*)U + (size_t)(lrow0 + row) * (UCOLS * 2) +
               (size_t)(c0 + h * 32 + o * 8) * 2) = v;
    }
  }
}

// ------------------------------------------------------------- fused attention
// 1 wave = 1 batch row. No LDS. Pass1: stream A (HBM) lane-spread d=64k+l,
// 4 head-dots vs u, 64-lane butterfly. Softmax per lane (h=l&3).
// Pass2: re-stream A (L2-hot) d=16k+(l>>2), accumulate w[h=l&3], store bf16.
__global__ __launch_bounds__(256, 4) void attn_f(
    const unsigned short* __restrict__ U, const float* __restrict__ nbrF,
    const float* __restrict__ edgeF, const float* __restrict__ timeF,
    const int* __restrict__ masks, unsigned short* __restrict__ W, int b0) {
  const int w = threadIdx.x >> 6, l = threadIdx.x & 63;
  const int lb = blockIdx.x * 4 + w;          // local (chunk) row
  const int b = b0 + lb;                      // global row
  const unsigned short* up = U + (size_t)lb * UCOLS;
  float uf[4][7];
#pragma unroll
  for (int h = 0; h < 4; ++h)
#pragma unroll
    for (int k = 0; k < 7; ++k) uf[h][k] = bf2f(up[h * UD + k * 64 + l]);
  // masks -> bitmask
  const int* mp = masks + (size_t)b * 20;
  unsigned mbits = 0;
#pragma unroll
  for (int j = 0; j < 5; ++j) {
    const int4 mm = *(const int4*)(mp + j * 4);
    mbits |= (mm.x != 0 ? 1u : 0u) << (j * 4);
    mbits |= (mm.y != 0 ? 1u : 0u) << (j * 4 + 1);
    mbits |= (mm.z != 0 ? 1u : 0u) << (j * 4 + 2);
    mbits |= (mm.w != 0 ? 1u : 0u) << (j * 4 + 3);
  }
  // pass-1 pointers (per-lane region; d>=444 lanes hit uf==0, safe dummy addr)
  const float* pk[7]; int st[7];
#pragma unroll
  for (int k = 0; k < 7; ++k) {
    const int d = k * 64 + l;
    if (d < NODE_D)        { pk[k] = nbrF  + (size_t)b * (20 * NODE_D) + d;            st[k] = NODE_D; }
    else if (d < 2*NODE_D) { pk[k] = edgeF + (size_t)b * (20 * NODE_D) + (d - NODE_D); st[k] = NODE_D; }
    else if (d < KEY_D)    { pk[k] = timeF + (size_t)b * (20 * TIME_D) + (d - 2*NODE_D); st[k] = TIME_D; }
    else                   { pk[k] = timeF + (size_t)b * (20 * TIME_D);                st[k] = 0; }
  }
  float s[20];
  float Ac[7], An[7];
#pragma unroll
  for (int k = 0; k < 7; ++k) { Ac[k] = *pk[k]; pk[k] += st[k]; }
#pragma unroll
  for (int n = 0; n < 20; ++n) {
    if (n < 19) {
#pragma unroll
      for (int k = 0; k < 7; ++k) { An[k] = *pk[k]; pk[k] += st[k]; }
    }
    float p0 = 0.f, p1 = 0.f, p2 = 0.f, p3 = 0.f;
#pragma unroll
    for (int k = 0; k < 7; ++k) {
      p0 += Ac[k] * uf[0][k]; p1 += Ac[k] * uf[1][k];
      p2 += Ac[k] * uf[2][k]; p3 += Ac[k] * uf[3][k];
    }
#pragma unroll
    for (int o = 32; o; o >>= 1) {
      p0 += __shfl_xor(p0, o); p1 += __shfl_xor(p1, o);
      p2 += __shfl_xor(p2, o); p3 += __shfl_xor(p3, o);
    }
    const float s01 = (l & 1) ? p1 : p0, s23 = (l & 1) ? p3 : p2;
    s[n] = (l & 2) ? s23 : s01;
#pragma unroll
    for (int k = 0; k < 7; ++k) Ac[k] = An[k];
  }
  // softmax (lane's head = l&3)
  const float scale = 0.12126781251816648f;  // 68^-0.5
  float mx = -1e30f;
#pragma unroll
  for (int n = 0; n < 20; ++n) {
    s[n] = ((mbits >> n) & 1u) ? s[n] * scale : -1e10f;
    mx = fmaxf(mx, s[n]);
  }
  float sum = 0.f;
#pragma unroll
  for (int n = 0; n < 20; ++n) { s[n] = __expf(s[n] - mx); sum += s[n]; }
  const float inv = 1.f / sum;
#pragma unroll
  for (int n = 0; n < 20; ++n) s[n] *= inv;
  // pass-2: w[h,d] = sum_n p_n * a_n[d], d = k*16 + (l>>2), h = l&3
  const int rr = l >> 2, h2 = l & 3;
  unsigned short* wp = W + (size_t)b * UCOLS + (size_t)h2 * UD;
#pragma unroll 4
  for (int k = 0; k < 28; ++k) {
    const int d2 = k * 16 + rr;
    const float* p2; int s2; bool ok = true;
    if (d2 < NODE_D)        { p2 = nbrF  + (size_t)b * (20 * NODE_D) + d2;             s2 = NODE_D; }
    else if (d2 < 2*NODE_D) { p2 = edgeF + (size_t)b * (20 * NODE_D) + (d2 - NODE_D);  s2 = NODE_D; }
    else if (d2 < KEY_D)    { p2 = timeF + (size_t)b * (20 * TIME_D) + (d2 - 2*NODE_D); s2 = TIME_D; }
    else                    { p2 = timeF + (size_t)b * (20 * TIME_D);                  s2 = 0; ok = false; }
    float acc = 0.f;
#pragma unroll
    for (int n = 0; n < 20; ++n) acc += s[n] * p2[(size_t)n * s2];
    wp[d2] = f2bf(ok ? acc : 0.f);
  }
}

// ------------------------------------------------------------- final = w@M2 +LN
// Block 64 rows, wave = 16 rows x 272 cols (17 frags), K=1792 (56 ks).
// A (w rows) streamed from global (L3-hot), B (M2p) fragment-packed L2-hot.
__global__ __launch_bounds__(256) void fc2_ln(
    const unsigned short* __restrict__ Wbuf, const unsigned short* __restrict__ M2p,
    const float* __restrict__ nodeF, const float* __restrict__ timeF,
    const float* __restrict__ brv, const float* __restrict__ gammav,
    const float* __restrict__ betav, float* __restrict__ Out) {
  const int t = threadIdx.x;
  const int w = t >> 6, l = t & 63, l15 = l & 15, quad = l >> 4;
  const int m0 = blockIdx.x * 64;
  const unsigned short* ap =
      Wbuf + (size_t)(m0 + w * 16 + l15) * UCOLS + quad * 8;
  f32x4 acc[17];
#pragma unroll
  for (int nf = 0; nf < 17; ++nf) acc[nf] = (f32x4){0, 0, 0, 0};
  bfx8 a0 = *(const bfx8*)ap;
#pragma unroll 2
  for (int ks = 0; ks < M_KS; ++ks) {
    const bfx8 a1 = (ks + 1 < M_KS) ? *(const bfx8*)(ap + (ks + 1) * 32) : a0;
#pragma unroll
    for (int nf = 0; nf < 17; ++nf) {
      const bfx8 bfr =
          *(const bfx8*)(M2p + ((size_t)(ks * 17 + nf) * 64 + l) * 8);
      acc[nf] = __builtin_amdgcn_mfma_f32_16x16x32_bf16(a0, bfr, acc[nf], 0, 0, 0);
    }
    a0 = a1;
  }
  float sum[4] = {0.f, 0.f, 0.f, 0.f}, sq[4] = {0.f, 0.f, 0.f, 0.f};
#pragma unroll
  for (int nf = 0; nf < 17; ++nf) {
    const int col = nf * 16 + l15;
    const float bias = brv[col];
#pragma unroll
    for (int r = 0; r < 4; ++r) {
      const size_t row = m0 + w * 16 + quad * 4 + r;
      const float res = (col < NODE_D) ? nodeF[row * NODE_D + col]
                                       : timeF[row * TIME_D + (col - NODE_D)];
      const float x = acc[nf][r] + bias + res;
      acc[nf][r] = x;
      sum[r] += x; sq[r] += x * x;
    }
  }
#pragma unroll
  for (int r = 0; r < 4; ++r)
#pragma unroll
    for (int o = 1; o < 16; o <<= 1) {
      sum[r] += __shfl_xor(sum[r], o);
      sq[r]  += __shfl_xor(sq[r], o);
    }
  float mean[4], rstd[4];
#pragma unroll
  for (int r = 0; r < 4; ++r) {
    mean[r] = sum[r] * (1.f / OUT_D);
    const float var = sq[r] * (1.f / OUT_D) - mean[r] * mean[r];
    rstd[r] = rsqrtf(var + 1e-5f);
  }
#pragma unroll
  for (int nf = 0; nf < 17; ++nf) {
    const int col = nf * 16 + l15;
    const float g_ = gammav[col], b_ = betav[col];
#pragma unroll
    for (int r = 0; r < 4; ++r) {
      const size_t row = m0 + w * 16 + quad * 4 + r;
      Out[row * OUT_D + col] = (acc[nf][r] - mean[r]) * rstd[r] * g_ + b_;
    }
  }
}

// ---------------------------------------------------------------- launch
extern "C" void kernel_launch(void* const* d_in, const int* in_sizes, int n_in,
                              void* d_out, int out_size, void* d_ws, size_t ws_size,
                              hipStream_t stream) {
  const float* nodeF = (const float*)d_in[0];
  const float* ntime = (const float*)d_in[1];
  const float* nbrF  = (const float*)d_in[2];
  const float* nbrT  = (const float*)d_in[3];
  const float* nbrE  = (const float*)d_in[4];
  const int*   mask  = (const int*)d_in[5];
  const float* Wq = (const float*)d_in[6];
  const float* Wk = (const float*)d_in[7];
  const float* Wv = (const float*)d_in[8];
  const float* Wr = (const float*)d_in[9];
  const float* brv = (const float*)d_in[10];
  const float* gv  = (const float*)d_in[11];
  const float* bv  = (const float*)d_in[12];
  float* out = (float*)d_out;

  char* p = (char*)d_ws;
  auto take = [&](size_t bytes) {
    char* q = p; p += (bytes + 255) & ~(size_t)255; return q;
  };
  unsigned short* Gp  = (unsigned short*)take((size_t)GP_N * 8 * 2);
  unsigned short* M2p = (unsigned short*)take((size_t)MP_N * 8 * 2);
  unsigned short* Uc  = (unsigned short*)take((size_t)CB2 * UCOLS * 2);
  unsigned short* Wb  = (unsigned short*)take((size_t)B_TOT * UCOLS * 2);

  pack_gm<<<dim3((GP_N + MP_N) / 256), dim3(256), 0, stream>>>(
      Wq, Wk, Wv, Wr, Gp, M2p);
  for (int c = 0; c < NCH; ++c) {
    u_gemm<<<dim3(7 * (CB2 / 64)), dim3(256), 0, stream>>>(
        nodeF, ntime, Gp, Uc, c * CB2);
    attn_f<<<dim3(CB2 / 4), dim3(256), 0, stream>>>(
        Uc, nbrF, nbrE, nbrT, mask, Wb, c * CB2);
  }
  fc2_ln<<<dim3(B_TOT / 64), dim3(256), 0, stream>>>(
      Wb, M2p, nodeF, ntime, brv, gv, bv, out);
}